// Round 7
// baseline (3748.836 us; speedup 1.0000x reference)
//
#include <hip/hip_runtime.h>
#include <cmath>

#define Bc 32
#define Tc 32
#define Sc 64
#define Hc 512
#define Ec 512
#define Vc 32000
#define NEGC (-1e9f)
#define BH (Bc * Hc)
#define Mtot ((Tc - 1) * Bc)   // 992
#define NBLK 256
#define SLOT_PAD 32            // one 128B line per arrival slot

__device__ __forceinline__ float sigf(float x) { return 1.0f / (1.0f + expf(-x)); }

__device__ __forceinline__ float dot4(const float* a, const float* b) {
    float4 x = *(const float4*)a;
    float4 y = *(const float4*)b;
    return x.x * y.x + x.y * y.y + x.z * y.z + x.w * y.w;
}

// Same expression tree as dot4, on preloaded registers (load/compute split so
// batches of loads can be in flight; accumulate ORDER is never changed).
__device__ __forceinline__ float d4v(float4 x, float4 y) {
    return x.x * y.x + x.y * y.y + x.z * y.z + x.w * y.w;
}

// Write-through store to the device coherence point. Used for all data that
// crosses a grid barrier; those buffers rotate per step (write-once addresses)
// so cached reads can never see stale lines -> barrier needs no cache maint.
__device__ __forceinline__ void stg(float* p, float v) {
    __hip_atomic_store(p, v, __ATOMIC_RELAXED, __HIP_MEMORY_SCOPE_AGENT);
}

// All-to-all grid barrier (1 LLC hop):
//  - arrival: each block's thread 0 stores gen to its OWN 128B-padded slot
//  - detection: EVERY thread of EVERY block polls one slot (thread i -> slot i)
//    -> no block-0 gather, no go-broadcast: detection = last arrival + 1 round.
// (round 5/6 showed fan-out is not the cost; the 3-hop arrival->detect->release
//  chain was. This removes 2 hops.)
// No cache-maintenance instructions (see stg comment). vmcnt(0) drains this
// wave's through-stores to the coherence point before signaling arrival.
__device__ __forceinline__ void gbar(unsigned int* slots, unsigned int gen) {
    asm volatile("s_waitcnt vmcnt(0)" ::: "memory");
    __syncthreads();
    if (threadIdx.x == 0)
        __hip_atomic_store(&slots[blockIdx.x * SLOT_PAD], gen,
                           __ATOMIC_RELAXED, __HIP_MEMORY_SCOPE_AGENT);
    const unsigned int* p = &slots[threadIdx.x * SLOT_PAD];
    while (__hip_atomic_load(p, __ATOMIC_RELAXED, __HIP_MEMORY_SCOPE_AGENT) < gen)
        __builtin_amdgcn_s_sleep(1);
    __syncthreads();
    asm volatile("" ::: "memory");
}

// proj[b][s][k] = sum_h W_a[k][h] * enc[s][b][h]   (+ resets barrier state)
__global__ __launch_bounds__(256) void k_proj(const float* __restrict__ W_a,
                                              const float* __restrict__ enc,
                                              float* __restrict__ proj,
                                              unsigned int* __restrict__ bar) {
    if (blockIdx.x == 0 && blockIdx.y == 0 && blockIdx.z == 0)
        bar[threadIdx.x * SLOT_PAD] = 0u;   // arrival slots (flushed at dispatch end)
    int k = blockIdx.x * 256 + threadIdx.x;
    int s0 = blockIdx.y * 8;
    int b = blockIdx.z;
    __shared__ float se[8][Hc];
    for (int i = threadIdx.x; i < 8 * Hc; i += 256) {
        int ss = i >> 9, hh = i & (Hc - 1);
        se[ss][hh] = enc[((size_t)(s0 + ss) * Bc + b) * Hc + hh];
    }
    __syncthreads();
    const float* wr = W_a + (size_t)k * Hc;
    float acc[8];
#pragma unroll
    for (int ss = 0; ss < 8; ++ss) acc[ss] = 0.0f;
    for (int h = 0; h < Hc; h += 4) {
        float4 w = *(const float4*)(wr + h);
#pragma unroll
        for (int ss = 0; ss < 8; ++ss) {
            acc[ss] = fmaf(w.x, se[ss][h + 0], acc[ss]);
            acc[ss] = fmaf(w.y, se[ss][h + 1], acc[ss]);
            acc[ss] = fmaf(w.z, se[ss][h + 2], acc[ss]);
            acc[ss] = fmaf(w.w, se[ss][h + 3], acc[ss]);
        }
    }
#pragma unroll
    for (int ss = 0; ss < 8; ++ss)
        proj[((size_t)b * Sc + s0 + ss) * Hc + k] = acc[ss];
}

// Persistent decode loop, 3 barriers/step:
//  phase 1 (all 256 blocks): gates GEMM + LSTM        == k_step1 chains
//  phase 2/3 (blocks 0..31): score+softmax+ctx->ctxN  == k_score/k_ctx chains
//  phase 4 (all 256 blocks): Wc GEMV, 2 fixed W_c rows/block, 4 lanes/output
// Weight rows are block-fixed -> per-XCD working set < 4MB L2 (verified:
// FETCH 73MB). Phase-1/4 GEMV loops issue 32-float load batches up front
// (occupancy is grid-limited at 1 wave/SIMD, so VGPRs are free and exposed
// L2 latency is the phase cost); accumulate order is bit-identical.
__global__ __launch_bounds__(256) void k_loop(
    const int* __restrict__ tgt, const int* __restrict__ len_src,
    const float* __restrict__ enc, const float* __restrict__ h0,
    const float* __restrict__ c0, const float* __restrict__ emb,
    const float* __restrict__ W_ih, const float* __restrict__ W_hh,
    const float* __restrict__ b_ih, const float* __restrict__ b_hh,
    const float* __restrict__ proj, const float* __restrict__ W_c,
    const float* __restrict__ b_c,
    float* __restrict__ h_all, float* __restrict__ cbuf,
    float* __restrict__ ah_all, float* __restrict__ ctx_all,
    unsigned int* __restrict__ bar) {
    int blk = blockIdx.x, tid = threadIdx.x;
    unsigned int gen = 0;

    // prologue == k_init (write-through: read cross-XCD after the barrier)
    {
        int i = blk * 256 + tid;
        if (i < BH) {
            stg(&h_all[i], h0[i]);
            stg(&cbuf[i], c0[i]);
            stg(&ah_all[i], 0.0f);
        }
    }
    gbar(bar, ++gen);

    __shared__ float sg[2][4][32];
    __shared__ __align__(16) float sh[Hc];    // h2 for this batch (blocks<32)
    __shared__ float ss[Sc];
    __shared__ float sal[Sc];

    for (int t = 0; t < Tc - 1; ++t) {
        const float* hP = h_all + (size_t)t * BH;
        float*       hN = h_all + (size_t)(t + 1) * BH;
        const float* aP = ah_all + (size_t)t * BH;
        float*       aN = ah_all + (size_t)(t + 1) * BH;
        float*       ctxN = ctx_all + (size_t)t * BH;

        // ---------------- phase 1: k_step1 (all 256 blocks) ----------------
        {
            int b  = tid & 31;
            int q  = (tid >> 5) & 3;
            int hl = tid >> 7;
            int h  = blk * 2 + hl;
            int j  = q * Hc + h;
            int w  = tgt[b * Tc + t];
            const float* x  = emb + (size_t)w * Ec;
            const float* wi = W_ih + (size_t)j * (Ec + Hc);
            const float* wh = W_hh + (size_t)j * Hc;
            const float* ap = aP + b * Hc;
            const float* hp = hP + b * Hc;
            float a0 = 0.f, a1 = 0.f, a2 = 0.f, a3 = 0.f;
            // 32-float batches: 16 loads in flight, then the ORIGINAL
            // accumulate order a0,a1,a2,a3 (16-step) twice. Bit-identical.
            for (int e = 0; e < Ec; e += 32) {
                float4 xv[8], wv[8];
#pragma unroll
                for (int i = 0; i < 8; ++i) {
                    xv[i] = *(const float4*)(x + e + 4 * i);
                    wv[i] = *(const float4*)(wi + e + 4 * i);
                }
                a0 += d4v(xv[0], wv[0]); a1 += d4v(xv[1], wv[1]);
                a2 += d4v(xv[2], wv[2]); a3 += d4v(xv[3], wv[3]);
                a0 += d4v(xv[4], wv[4]); a1 += d4v(xv[5], wv[5]);
                a2 += d4v(xv[6], wv[6]); a3 += d4v(xv[7], wv[7]);
            }
            for (int k = 0; k < Hc; k += 32) {
                float4 xv[8], wv[8];
#pragma unroll
                for (int i = 0; i < 8; ++i) {
                    xv[i] = *(const float4*)(ap + k + 4 * i);
                    wv[i] = *(const float4*)(wi + Ec + k + 4 * i);
                }
                a0 += d4v(xv[0], wv[0]); a1 += d4v(xv[1], wv[1]);
                a2 += d4v(xv[2], wv[2]); a3 += d4v(xv[3], wv[3]);
                a0 += d4v(xv[4], wv[4]); a1 += d4v(xv[5], wv[5]);
                a2 += d4v(xv[6], wv[6]); a3 += d4v(xv[7], wv[7]);
            }
            for (int k = 0; k < Hc; k += 32) {
                float4 xv[8], wv[8];
#pragma unroll
                for (int i = 0; i < 8; ++i) {
                    xv[i] = *(const float4*)(hp + k + 4 * i);
                    wv[i] = *(const float4*)(wh + k + 4 * i);
                }
                a0 += d4v(xv[0], wv[0]); a1 += d4v(xv[1], wv[1]);
                a2 += d4v(xv[2], wv[2]); a3 += d4v(xv[3], wv[3]);
                a0 += d4v(xv[4], wv[4]); a1 += d4v(xv[5], wv[5]);
                a2 += d4v(xv[6], wv[6]); a3 += d4v(xv[7], wv[7]);
            }
            float acc = b_ih[j] + b_hh[j] + ((a0 + a1) + (a2 + a3));
            sg[hl][q][b] = acc;
            __syncthreads();
            if (q == 0) {
                float iv = sigf(sg[hl][0][b]);
                float fv = sigf(sg[hl][1][b]);
                float gv = tanhf(sg[hl][2][b]);
                float ov = sigf(sg[hl][3][b]);
                int idx = b * Hc + h;
                float c2 = fv * cbuf[idx] + iv * gv;
                float h2v = ov * tanhf(c2);
                cbuf[idx] = c2;        // same-thread read/write only: cacheable
                stg(&hN[idx], h2v);    // crosses barrier: write-through
            }
        }
        gbar(bar, ++gen);

        // --------- phase 2/3: k_score + k_ctx (blocks 0..31, b=blk) ---------
        if (blk < Bc) {
            int b = blk;
            for (int k = tid; k < Hc; k += 256) sh[k] = hN[b * Hc + k];
            __syncthreads();
            // scores (k_score chain)
            {
                int s = tid >> 2, r = tid & 3;
                const float* pr = proj + ((size_t)b * Sc + s) * Hc + r * 128;
                const float* hh = sh + r * 128;
                float p0 = 0.f, p1 = 0.f;
                for (int k = 0; k < 128; k += 8) {
                    p0 += dot4(hh + k, pr + k);
                    p1 += dot4(hh + k + 4, pr + k + 4);
                }
                float p = p0 + p1;
                p += __shfl_xor(p, 1);
                p += __shfl_xor(p, 2);
                if (r == 0) ss[s] = p;
            }
            __syncthreads();
            // masked softmax (k_score chain), lanes 0..63 of wave 0
            if (tid < Sc) {
                int len = len_src[b];
                float sc = (tid < len) ? ss[tid] : NEGC;
                float mx = sc;
#pragma unroll
                for (int m = 32; m >= 1; m >>= 1) mx = fmaxf(mx, __shfl_xor(mx, m));
                float p = expf(sc - mx);
                float sum = p;
#pragma unroll
                for (int m = 32; m >= 1; m >>= 1) sum += __shfl_xor(sum, m);
                sal[tid] = p / sum;
            }
            __syncthreads();
            // ctx (k_ctx chain): per h, two 32-long serial chains + one add
#pragma unroll
            for (int rep = 0; rep < 2; ++rep) {
                int h = tid + rep * 256;
                float accA = 0.0f, accB = 0.0f;
                for (int s = 0; s < 32; ++s)
                    accA = fmaf(sal[s], enc[((size_t)s * Bc + b) * Hc + h], accA);
                for (int s = 32; s < 64; ++s)
                    accB = fmaf(sal[s], enc[((size_t)s * Bc + b) * Hc + h], accB);
                stg(&ctxN[b * Hc + h], accA + accB);
            }
        }
        gbar(bar, ++gen);

        // ------------- phase 4: Wc GEMV (all 256 blocks) -------------
        // block owns W_c rows {2*blk, 2*blk+1} (same rows every step -> L2-hit).
        // 4 lanes per output compute the k_wc a0..a3 sub-chains; combine
        // ((a0+a1)+(a2+a3)) via xor-shuffles (fp add is bitwise commutative).
        {
            int r   = tid & 3;          // sub-chain index 0..3
            int out = tid >> 2;         // 0..63
            int b   = out >> 1;
            int kl  = out & 1;
            int k   = blk * 2 + kl;
            const float* wc  = W_c + (size_t)k * (2 * Hc) + 4 * r;
            const float* wc2 = wc + Hc;
            const float* hp  = hN + b * Hc + 4 * r;
            const float* cp  = ctxN + b * Hc + 4 * r;
            float ar = 0.f;
            // 4-iteration load batches; chain order preserved (sequential).
            for (int j = 0; j < Hc; j += 64) {
                float4 hv[4], wv[4];
#pragma unroll
                for (int i = 0; i < 4; ++i) {
                    hv[i] = *(const float4*)(hp + j + 16 * i);
                    wv[i] = *(const float4*)(wc + j + 16 * i);
                }
                ar += d4v(hv[0], wv[0]); ar += d4v(hv[1], wv[1]);
                ar += d4v(hv[2], wv[2]); ar += d4v(hv[3], wv[3]);
            }
            for (int j = 0; j < Hc; j += 64) {
                float4 hv[4], wv[4];
#pragma unroll
                for (int i = 0; i < 4; ++i) {
                    hv[i] = *(const float4*)(cp + j + 16 * i);
                    wv[i] = *(const float4*)(wc2 + j + 16 * i);
                }
                ar += d4v(hv[0], wv[0]); ar += d4v(hv[1], wv[1]);
                ar += d4v(hv[2], wv[2]); ar += d4v(hv[3], wv[3]);
            }
            float v01 = ar + __shfl_xor(ar, 1);   // (a0+a1) on lanes 0/1 pairs
            float v   = v01 + __shfl_xor(v01, 2); // ((a0+a1)+(a2+a3))
            if (r == 0)
                stg(&aN[b * Hc + k], tanhf(b_c[k] + v));
        }
        gbar(bar, ++gen);
    }
}

// Batched logits GEMM: C[m][n] = A[m][:] . W_o[n][:] + b_o[n]
__global__ __launch_bounds__(256) void k_biglogits(const float* __restrict__ A,
                                                   const float* __restrict__ W_o,
                                                   const float* __restrict__ b_o,
                                                   float* __restrict__ out) {
    __shared__ float At[32][128];
    __shared__ float Bt[32][128];
    int tid = threadIdx.x;
    int n_base = blockIdx.x * 128;
    int m_base = blockIdx.y * 128;
    int tn = tid & 15, tm = tid >> 4;

    float acc[2][4][2][4];
#pragma unroll
    for (int mg = 0; mg < 2; ++mg)
#pragma unroll
        for (int mi = 0; mi < 4; ++mi)
#pragma unroll
            for (int ng = 0; ng < 2; ++ng)
#pragma unroll
                for (int ni = 0; ni < 4; ++ni) acc[mg][mi][ng][ni] = 0.0f;

    int srow = tid >> 1;
    int koff = (tid & 1) * 16;
    int gm = m_base + srow;
    const float* arow = A + (size_t)gm * Hc + koff;
    const float* brow = W_o + (size_t)(n_base + srow) * Hc + koff;

    for (int kc = 0; kc < Hc; kc += 32) {
        float av[16], bv[16];
#pragma unroll
        for (int i = 0; i < 4; ++i) {
            float4 t4 = (gm < Mtot) ? *(const float4*)(arow + kc + i * 4)
                                    : make_float4(0.f, 0.f, 0.f, 0.f);
            av[i * 4 + 0] = t4.x; av[i * 4 + 1] = t4.y; av[i * 4 + 2] = t4.z; av[i * 4 + 3] = t4.w;
            float4 u4 = *(const float4*)(brow + kc + i * 4);
            bv[i * 4 + 0] = u4.x; bv[i * 4 + 1] = u4.y; bv[i * 4 + 2] = u4.z; bv[i * 4 + 3] = u4.w;
        }
        __syncthreads();
#pragma unroll
        for (int i = 0; i < 16; ++i) {
            At[koff + i][srow] = av[i];
            Bt[koff + i][srow] = bv[i];
        }
        __syncthreads();
#pragma unroll
        for (int k = 0; k < 32; ++k) {
            float4 a0 = *(const float4*)&At[k][tm * 4];
            float4 a1 = *(const float4*)&At[k][64 + tm * 4];
            float4 b0 = *(const float4*)&Bt[k][tn * 4];
            float4 b1 = *(const float4*)&Bt[k][64 + tn * 4];
            float am[2][4] = {{a0.x, a0.y, a0.z, a0.w}, {a1.x, a1.y, a1.z, a1.w}};
            float bn[2][4] = {{b0.x, b0.y, b0.z, b0.w}, {b1.x, b1.y, b1.z, b1.w}};
#pragma unroll
            for (int mg = 0; mg < 2; ++mg)
#pragma unroll
                for (int mi = 0; mi < 4; ++mi)
#pragma unroll
                    for (int ng = 0; ng < 2; ++ng)
#pragma unroll
                        for (int ni = 0; ni < 4; ++ni)
                            acc[mg][mi][ng][ni] = fmaf(am[mg][mi], bn[ng][ni], acc[mg][mi][ng][ni]);
        }
        __syncthreads();
    }

#pragma unroll
    for (int ng = 0; ng < 2; ++ng) {
        int n = n_base + ng * 64 + tn * 4;
        float4 bo = *(const float4*)(b_o + n);
#pragma unroll
        for (int mg = 0; mg < 2; ++mg)
#pragma unroll
            for (int mi = 0; mi < 4; ++mi) {
                int m = m_base + mg * 64 + tm * 4 + mi;
                if (m < Mtot) {
                    float4 v;
                    v.x = acc[mg][mi][ng][0] + bo.x;
                    v.y = acc[mg][mi][ng][1] + bo.y;
                    v.z = acc[mg][mi][ng][2] + bo.z;
                    v.w = acc[mg][mi][ng][3] + bo.w;
                    *(float4*)(out + (size_t)m * Vc + n) = v;
                }
            }
    }
}

// Per row m: argmax (first tiebreak) + logsumexp, then subtract in place; words out.
__global__ __launch_bounds__(256) void k_reduce_norm(float* __restrict__ out,
                                                     float* __restrict__ words) {
    int m = blockIdx.x, tid = threadIdx.x;
    float* row = out + (size_t)m * Vc;
    float mx = -INFINITY;
    int mi = 0;
    for (int v = tid; v < Vc; v += 256) {
        float x = row[v];
        if (x > mx) { mx = x; mi = v; }
    }
    __shared__ float smx[256];
    __shared__ int smi[256];
    __shared__ float ssum[256];
    smx[tid] = mx; smi[tid] = mi;
    __syncthreads();
    for (int off = 128; off; off >>= 1) {
        if (tid < off) {
            float o = smx[tid + off]; int oi = smi[tid + off];
            if (o > smx[tid] || (o == smx[tid] && oi < smi[tid])) { smx[tid] = o; smi[tid] = oi; }
        }
        __syncthreads();
    }
    float gmx = smx[0];
    float s = 0.0f;
    for (int v = tid; v < Vc; v += 256) s += expf(row[v] - gmx);
    ssum[tid] = s;
    __syncthreads();
    for (int off = 128; off; off >>= 1) {
        if (tid < off) ssum[tid] += ssum[tid + off];
        __syncthreads();
    }
    float lse = gmx + logf(ssum[0]);
    __syncthreads();
    for (int v = tid; v < Vc; v += 256) row[v] -= lse;
    if (tid == 0) words[m] = (float)smi[0];
}

extern "C" void kernel_launch(void* const* d_in, const int* in_sizes, int n_in,
                              void* d_out, int out_size, void* d_ws, size_t ws_size,
                              hipStream_t stream) {
    const int*   tgt     = (const int*)d_in[0];
    const int*   len_src = (const int*)d_in[1];
    const float* enc     = (const float*)d_in[2];
    const float* h0      = (const float*)d_in[3];
    const float* c0      = (const float*)d_in[4];
    const float* emb     = (const float*)d_in[5];
    const float* W_ih    = (const float*)d_in[6];
    const float* W_hh    = (const float*)d_in[7];
    const float* b_ih    = (const float*)d_in[8];
    const float* b_hh    = (const float*)d_in[9];
    const float* W_a     = (const float*)d_in[10];
    const float* W_c     = (const float*)d_in[11];
    const float* b_c     = (const float*)d_in[12];
    const float* W_o     = (const float*)d_in[13];
    const float* b_o     = (const float*)d_in[14];

    float* out = (float*)d_out;
    float* ws = (float*)d_ws;

    float* proj    = ws;                             // B*S*H = 1,048,576
    float* h_all   = proj + (size_t)Bc * Sc * Hc;    // 32 * BH (write-once slots)
    float* cbuf    = h_all + 32 * (size_t)BH;        // BH (same-thread in-place)
    float* ah_all  = cbuf + BH;                      // 32 * BH (slot0 = zeros)
    float* ctx_all = ah_all + 32 * (size_t)BH;       // 31 * BH (write-once slots)
    unsigned int* bar = (unsigned int*)(ctx_all + 31 * (size_t)BH);
    float* out_words = out + (size_t)(Tc - 1) * Bc * Vc;

    {
        dim3 g(Hc / 256, Sc / 8, Bc);
        k_proj<<<g, 256, 0, stream>>>(W_a, enc, proj, bar);
    }

    k_loop<<<NBLK, 256, 0, stream>>>(tgt, len_src, enc, h0, c0, emb,
                                     W_ih, W_hh, b_ih, b_hh, proj, W_c, b_c,
                                     h_all, cbuf, ah_all, ctx_all, bar);

    {
        dim3 g(Vc / 128, (Mtot + 127) / 128);    // 250 x 8
        k_biglogits<<<g, 256, 0, stream>>>(ah_all + BH, W_o, b_o, out);
    }
    k_reduce_norm<<<Mtot, 256, 0, stream>>>(out, out_words);
}